// Round 6
// baseline (448.843 us; speedup 1.0000x reference)
//
#include <hip/hip_runtime.h>
#include <math.h>

#define HID   1024
#define VOCAB 50257
#define SEQ   4096

__device__ __forceinline__ float wave_sum(float v) {
    #pragma unroll
    for (int o = 32; o > 0; o >>= 1) v += __shfl_xor(v, o, 64);
    return v;
}
__device__ __forceinline__ float wave_max(float v) {
    #pragma unroll
    for (int o = 32; o > 0; o >>= 1) v = fmaxf(v, __shfl_xor(v, o, 64));
    return v;
}
__device__ __forceinline__ float sigmoidf(float x) {
    return 1.0f / (1.0f + expf(-x));
}
// monotone float<->int encode for atomicMax on non-NaN floats
__device__ __forceinline__ int enc_f(float f) {
    int k = __float_as_int(f);
    return k >= 0 ? k : k ^ 0x7FFFFFFF;
}
__device__ __forceinline__ float dec_f(int k) {
    return __int_as_float(k >= 0 ? k : k ^ 0x7FFFFFFF);
}

// Fused gates + LSTM cell. Block t (1024 blocks): wave w computes gate row
// w*1024+t of W_ih@x + W_hh@h; thread 0 finishes the cell for element t.
// Also zero-inits ctx and the reduction cells (ws is poisoned 0xAA each launch).
__global__ __launch_bounds__(256) void k_gates_lstm(
        const float* __restrict__ W_ih, const float* __restrict__ W_hh,
        const float* __restrict__ x, const float* __restrict__ h,
        const float* __restrict__ b_ih, const float* __restrict__ b_hh,
        const float* __restrict__ c_old,
        float* __restrict__ hnew, float* __restrict__ ctx,
        float* __restrict__ out_h, float* __restrict__ out_c,
        int* __restrict__ gmax, float* __restrict__ Ssum,
        int* __restrict__ lmax) {
    __shared__ float g4[4];
    int t = blockIdx.x;
    int wave = threadIdx.x >> 6, lane = threadIdx.x & 63;
    int row = wave * HID + t;
    const float4* wi = (const float4*)(W_ih + (size_t)row * HID);
    const float4* wh = (const float4*)(W_hh + (size_t)row * HID);
    const float4* xv = (const float4*)x;
    const float4* hv = (const float4*)h;
    float s = 0.f;
    #pragma unroll
    for (int i = 0; i < 4; ++i) {
        int idx = lane + 64 * i;
        float4 a = wi[idx], b = xv[idx];
        s += a.x * b.x + a.y * b.y + a.z * b.z + a.w * b.w;
        float4 c = wh[idx], d = hv[idx];
        s += c.x * d.x + c.y * d.y + c.z * d.z + c.w * d.w;
    }
    s = wave_sum(s);
    if (lane == 0) g4[wave] = s + b_ih[row] + b_hh[row];
    __syncthreads();
    if (threadIdx.x == 0) {
        float ig = sigmoidf(g4[0]);
        float fg = sigmoidf(g4[1]);
        float gg = tanhf(g4[2]);
        float og = sigmoidf(g4[3]);
        float cn = fg * c_old[t] + ig * gg;
        float hn = og * tanhf(cn);
        hnew[t] = hn; out_h[t] = hn; out_c[t] = cn;
        ctx[t] = 0.f;
        if (t == 0) {
            *gmax = (int)0x80000000;
            *lmax = (int)0x80000000;
            *Ssum = 0.f;
        }
    }
}

// scores[s] = dot(a[s,:], h_new); wave per row; block max -> atomicMax(gmax)
__global__ __launch_bounds__(256) void k_scores(
        const float* __restrict__ a, const float* __restrict__ h,
        float* __restrict__ scores, int* __restrict__ gmax) {
    __shared__ float bm[4];
    int wave = threadIdx.x >> 6, lane = threadIdx.x & 63;
    int row = blockIdx.x * 4 + wave;
    const float4* av = (const float4*)(a + (size_t)row * HID);
    const float4* hv = (const float4*)h;
    float s = 0.f;
    #pragma unroll
    for (int i = 0; i < 4; ++i) {
        int idx = lane + 64 * i;
        float4 p = av[idx], q = hv[idx];
        s += p.x * q.x + p.y * q.y + p.z * q.z + p.w * q.w;
    }
    s = wave_sum(s);
    if (lane == 0) { scores[row] = s; bm[wave] = s; }
    __syncthreads();
    if (threadIdx.x == 0) {
        float m = fmaxf(fmaxf(bm[0], bm[1]), fmaxf(bm[2], bm[3]));
        atomicMax(gmax, enc_f(m));
    }
}

// Unnormalized attention-weighted sum: ctx_u[col] += sum_s e_s * a[s,col],
// Ssum += sum_s e_s (normalization deferred to fc1).
// grid (4 col-blocks x 64 s-chunks), 256 threads.
__global__ __launch_bounds__(256) void k_ctx(
        const float* __restrict__ a, const float* __restrict__ scores,
        const int* __restrict__ gmax, float* __restrict__ ctx,
        float* __restrict__ Ssum) {
    __shared__ float e[64];
    int tid = threadIdx.x;
    int col = blockIdx.x * 256 + tid;
    int s0 = blockIdx.y * 64;
    float m = dec_f(*gmax);
    if (tid < 64) {
        float ev = expf(scores[s0 + tid] - m);
        e[tid] = ev;
        float ssum = wave_sum(ev);
        if (tid == 0 && blockIdx.x == 0) atomicAdd(Ssum, ssum);
    }
    __syncthreads();
    float acc = 0.f;
    #pragma unroll 8
    for (int j = 0; j < 64; ++j)
        acc += e[j] * a[(size_t)(s0 + j) * HID + col];
    atomicAdd(&ctx[col], acc);
}

// fc1_out[r] = dot(W[r,0:1024], ctx_u)/S + dot(W[r,1024:2048], h_new) + b[r]
__global__ __launch_bounds__(256) void k_fc1(
        const float* __restrict__ W, const float* __restrict__ ctx,
        const float* __restrict__ h, const float* __restrict__ b,
        const float* __restrict__ Ssum, float* __restrict__ out) {
    int wave = threadIdx.x >> 6, lane = threadIdx.x & 63;
    int row = blockIdx.x * 4 + wave;
    const float4* wr = (const float4*)(W + (size_t)row * 2 * HID);
    const float4* cv = (const float4*)ctx;
    const float4* hv = (const float4*)h;
    float sc = 0.f, sh = 0.f;
    #pragma unroll
    for (int i = 0; i < 4; ++i) {
        int idx = lane + 64 * i;
        float4 p = wr[idx], q = cv[idx];
        sc += p.x * q.x + p.y * q.y + p.z * q.z + p.w * q.w;
        float4 r = wr[256 + idx], t = hv[idx];
        sh += r.x * t.x + r.y * t.y + r.z * t.z + r.w * t.w;
    }
    sc = wave_sum(sc);
    sh = wave_sum(sh);
    if (lane == 0) out[row] = sc / (*Ssum) + sh + b[row];
}

// logits[r] = dot(fc2_w[r,:], v) + b[r]; wave per row; 50257 rows (dominant).
// Also folds the global logits-max into lmax via one atomic per block, so the
// LSE kernel needs only a single (sum) pass.
__global__ __launch_bounds__(256) void k_fc2(
        const float* __restrict__ W, const float* __restrict__ v,
        const float* __restrict__ b, float* __restrict__ out,
        int* __restrict__ lmax) {
    __shared__ float bm[4];
    int wave = threadIdx.x >> 6, lane = threadIdx.x & 63;
    int row = blockIdx.x * 4 + wave;
    int valid = row < VOCAB;
    int rv = valid ? row : (VOCAB - 1);   // tail waves redo a valid row
    const float4* wr = (const float4*)(W + (size_t)rv * HID);
    const float4* vv = (const float4*)v;
    float s = 0.f;
    #pragma unroll
    for (int i = 0; i < 4; ++i) {
        int idx = lane + 64 * i;
        float4 p = wr[idx], q = vv[idx];
        s += p.x * q.x + p.y * q.y + p.z * q.z + p.w * q.w;
    }
    s = wave_sum(s);
    if (lane == 0) {
        float val = s + b[rv];
        if (valid) out[row] = val;
        bm[wave] = valid ? val : -INFINITY;
    }
    __syncthreads();
    if (threadIdx.x == 0) {
        float m = fmaxf(fmaxf(bm[0], bm[1]), fmaxf(bm[2], bm[3]));
        atomicMax(lmax, enc_f(m));
    }
}

// Single sum-pass LSE: max already in lmax. One block, float4 bulk loads.
__global__ __launch_bounds__(1024) void k_lse(
        const float* __restrict__ logits, const int* __restrict__ lmax,
        float* __restrict__ red_out) {
    __shared__ float red[16];
    int tid = threadIdx.x, wave = tid >> 6, lane = tid & 63;
    float m = dec_f(*lmax);
    const float4* lv = (const float4*)logits;
    const int N4 = VOCAB / 4;            // 12564 float4 = 50256 elements
    float s = (tid == 0) ? expf(logits[VOCAB - 1] - m) : 0.f;
    for (int i = tid; i < N4; i += 1024) {
        float4 v = lv[i];
        s += expf(v.x - m) + expf(v.y - m) + expf(v.z - m) + expf(v.w - m);
    }
    s = wave_sum(s);
    if (lane == 0) red[wave] = s;
    __syncthreads();
    if (tid < 64) {
        float ss = (tid < 16) ? red[tid] : 0.f;
        ss = wave_sum(ss);
        if (tid == 0) { red_out[0] = m; red_out[1] = logf(ss); }
    }
}

// logp[i] = logits[i] - max - log(sumexp); float4 bulk + scalar tail
__global__ __launch_bounds__(256) void k_final(
        const float* __restrict__ logits, const float* __restrict__ red,
        float* __restrict__ out) {
    const int N4 = VOCAB / 4;
    int i = blockIdx.x * 256 + threadIdx.x;
    float c = red[0] + red[1];
    if (i < N4) {
        float4 v = ((const float4*)logits)[i];
        v.x -= c; v.y -= c; v.z -= c; v.w -= c;
        ((float4*)out)[i] = v;
    } else if (i == N4) {
        out[VOCAB - 1] = logits[VOCAB - 1] - c;
    }
}

extern "C" void kernel_launch(void* const* d_in, const int* in_sizes, int n_in,
                              void* d_out, int out_size, void* d_ws, size_t ws_size,
                              hipStream_t stream) {
    const float* attn  = (const float*)d_in[0];   // 4096 x 1024
    const float* x     = (const float*)d_in[1];   // 1024
    const float* h     = (const float*)d_in[2];   // 1024
    const float* c     = (const float*)d_in[3];   // 1024
    const float* W_ih  = (const float*)d_in[4];   // 4096 x 1024
    const float* W_hh  = (const float*)d_in[5];   // 4096 x 1024
    const float* b_ih  = (const float*)d_in[6];   // 4096
    const float* b_hh  = (const float*)d_in[7];   // 4096
    const float* fc1_w = (const float*)d_in[8];   // 1024 x 2048
    const float* fc1_b = (const float*)d_in[9];   // 1024
    const float* fc2_w = (const float*)d_in[10];  // 50257 x 1024
    const float* fc2_b = (const float*)d_in[11];  // 50257

    float* out = (float*)d_out;  // [logp 50257][h_new 1024][c_new 1024]
    float* ws  = (float*)d_ws;
    float* hnew   = ws;            // 1024
    float* scores = ws + 1024;     // 4096
    float* ctx    = ws + 5120;     // 1024 (unnormalized)
    float* fc1o   = ws + 6144;     // 1024
    float* logits = ws + 7168;     // 50257 (ends 57425)
    float* red    = ws + 57440;    // 2
    int*   gmax   = (int*)(ws + 57456);
    float* Ssum   = ws + 57457;
    int*   lmax   = (int*)(ws + 57458);

    k_gates_lstm<<<1024, 256, 0, stream>>>(W_ih, W_hh, x, h, b_ih, b_hh, c,
                                           hnew, ctx, out + VOCAB,
                                           out + VOCAB + HID, gmax, Ssum, lmax);
    k_scores    <<<1024, 256, 0, stream>>>(attn, hnew, scores, gmax);
    k_ctx       <<<dim3(4, 64), 256, 0, stream>>>(attn, scores, gmax, ctx, Ssum);
    k_fc1       <<<256, 256, 0, stream>>>(fc1_w, ctx, hnew, fc1_b, Ssum, fc1o);
    k_fc2       <<<(VOCAB + 3) / 4, 256, 0, stream>>>(fc2_w, fc1o, fc2_b,
                                                      logits, lmax);
    k_lse       <<<1, 1024, 0, stream>>>(logits, lmax, red);
    k_final     <<<(VOCAB / 4 + 256) / 256, 256, 0, stream>>>(logits, red, out);
}

// Round 7
// 369.510 us; speedup vs baseline: 1.2147x; 1.2147x over previous
//
#include <hip/hip_runtime.h>
#include <math.h>

#define HID   1024
#define VOCAB 50257
#define SEQ   4096
#define NLSE  13   // ceil(VOCAB / 4096) blocks for the partial LSE

__device__ __forceinline__ float wave_sum(float v) {
    #pragma unroll
    for (int o = 32; o > 0; o >>= 1) v += __shfl_xor(v, o, 64);
    return v;
}
__device__ __forceinline__ float wave_max(float v) {
    #pragma unroll
    for (int o = 32; o > 0; o >>= 1) v = fmaxf(v, __shfl_xor(v, o, 64));
    return v;
}
__device__ __forceinline__ float sigmoidf(float x) {
    return 1.0f / (1.0f + expf(-x));
}

// Fused gates + LSTM cell. Block t (1024 blocks): wave w computes gate row
// w*1024+t of W_ih@x + W_hh@h; thread 0 finishes the cell for element t.
// No atomics anywhere.
__global__ __launch_bounds__(256) void k_gates_lstm(
        const float* __restrict__ W_ih, const float* __restrict__ W_hh,
        const float* __restrict__ x, const float* __restrict__ h,
        const float* __restrict__ b_ih, const float* __restrict__ b_hh,
        const float* __restrict__ c_old,
        float* __restrict__ hnew,
        float* __restrict__ out_h, float* __restrict__ out_c) {
    __shared__ float g4[4];
    int t = blockIdx.x;
    int wave = threadIdx.x >> 6, lane = threadIdx.x & 63;
    int row = wave * HID + t;
    const float4* wi = (const float4*)(W_ih + (size_t)row * HID);
    const float4* wh = (const float4*)(W_hh + (size_t)row * HID);
    const float4* xv = (const float4*)x;
    const float4* hv = (const float4*)h;
    float s = 0.f;
    #pragma unroll
    for (int i = 0; i < 4; ++i) {
        int idx = lane + 64 * i;
        float4 a = wi[idx], b = xv[idx];
        s += a.x * b.x + a.y * b.y + a.z * b.z + a.w * b.w;
        float4 c = wh[idx], d = hv[idx];
        s += c.x * d.x + c.y * d.y + c.z * d.z + c.w * d.w;
    }
    s = wave_sum(s);
    if (lane == 0) g4[wave] = s + b_ih[row] + b_hh[row];
    __syncthreads();
    if (threadIdx.x == 0) {
        float ig = sigmoidf(g4[0]);
        float fg = sigmoidf(g4[1]);
        float gg = tanhf(g4[2]);
        float og = sigmoidf(g4[3]);
        float cn = fg * c_old[t] + ig * gg;
        float hn = og * tanhf(cn);
        hnew[t] = hn; out_h[t] = hn; out_c[t] = cn;
    }
}

// scores[s] = dot(a[s,:], h_new); wave per row; plain stores, no atomics.
__global__ __launch_bounds__(256) void k_scores(
        const float* __restrict__ a, const float* __restrict__ h,
        float* __restrict__ scores) {
    int wave = threadIdx.x >> 6, lane = threadIdx.x & 63;
    int row = blockIdx.x * 4 + wave;
    const float4* av = (const float4*)(a + (size_t)row * HID);
    const float4* hv = (const float4*)h;
    float s = 0.f;
    #pragma unroll
    for (int i = 0; i < 4; ++i) {
        int idx = lane + 64 * i;
        float4 p = av[idx], q = hv[idx];
        s += p.x * q.x + p.y * q.y + p.z * q.z + p.w * q.w;
    }
    s = wave_sum(s);
    if (lane == 0) scores[row] = s;
}

// softmax over 4096 scores, in-place -> normalized weights. Single block.
__global__ __launch_bounds__(1024) void k_softmax(float* __restrict__ scores) {
    __shared__ float red[32];  // [0:16) max partials, [16:32) sum partials
    int tid = threadIdx.x, wave = tid >> 6, lane = tid & 63;
    float4 v = ((const float4*)scores)[tid];
    float m = fmaxf(fmaxf(v.x, v.y), fmaxf(v.z, v.w));
    m = wave_max(m);
    if (lane == 0) red[wave] = m;
    __syncthreads();
    if (tid < 64) {
        float mm = (tid < 16) ? red[tid] : -INFINITY;
        mm = wave_max(mm);
        if (tid == 0) red[0] = mm;
    }
    __syncthreads();
    m = red[0];
    float4 e;
    e.x = expf(v.x - m); e.y = expf(v.y - m);
    e.z = expf(v.z - m); e.w = expf(v.w - m);
    float s = e.x + e.y + e.z + e.w;
    s = wave_sum(s);
    if (lane == 0) red[16 + wave] = s;
    __syncthreads();
    if (tid < 64) {
        float ss = (tid < 16) ? red[16 + tid] : 0.f;
        ss = wave_sum(ss);
        if (tid == 0) red[16] = ss;
    }
    __syncthreads();
    float inv = 1.0f / red[16];
    e.x *= inv; e.y *= inv; e.z *= inv; e.w *= inv;
    ((float4*)scores)[tid] = e;
}

// ctx partials: part[by][col] = sum_{s in chunk by} w[s] * a[s,col].
// grid (4 col-chunks x 64 seq-chunks), 256 threads. Plain stores only.
__global__ __launch_bounds__(256) void k_ctx_part(
        const float* __restrict__ a, const float* __restrict__ w,
        float* __restrict__ part) {
    __shared__ float e[64];
    int tid = threadIdx.x;
    int col = blockIdx.x * 256 + tid;
    int s0 = blockIdx.y * 64;
    if (tid < 64) e[tid] = w[s0 + tid];
    __syncthreads();
    float acc = 0.f;
    #pragma unroll 8
    for (int j = 0; j < 64; ++j)
        acc += e[j] * a[(size_t)(s0 + j) * HID + col];
    part[blockIdx.y * HID + col] = acc;
}

// ctx[col] = sum_j part[j][col]; 4 blocks x 256 threads, L2-resident reads.
__global__ __launch_bounds__(256) void k_ctx_red(
        const float* __restrict__ part, float* __restrict__ ctx) {
    int col = blockIdx.x * 256 + threadIdx.x;
    float acc = 0.f;
    #pragma unroll
    for (int j = 0; j < 64; ++j)
        acc += part[j * HID + col];
    ctx[col] = acc;
}

// fc1_out[r] = dot(W[r,0:1024], ctx) + dot(W[r,1024:2048], h_new) + b[r]
__global__ __launch_bounds__(256) void k_fc1(
        const float* __restrict__ W, const float* __restrict__ ctx,
        const float* __restrict__ h, const float* __restrict__ b,
        float* __restrict__ out) {
    int wave = threadIdx.x >> 6, lane = threadIdx.x & 63;
    int row = blockIdx.x * 4 + wave;
    const float4* wr = (const float4*)(W + (size_t)row * 2 * HID);
    const float4* cv = (const float4*)ctx;
    const float4* hv = (const float4*)h;
    float s = 0.f;
    #pragma unroll
    for (int i = 0; i < 4; ++i) {
        int idx = lane + 64 * i;
        float4 p = wr[idx], q = cv[idx];
        s += p.x * q.x + p.y * q.y + p.z * q.z + p.w * q.w;
        float4 r = wr[256 + idx], t = hv[idx];
        s += r.x * t.x + r.y * t.y + r.z * t.z + r.w * t.w;
    }
    s = wave_sum(s);
    if (lane == 0) out[row] = s + b[row];
}

// logits[r] = dot(fc2_w[r,:], v) + b[r]; wave per row; PURE matvec:
// no LDS, no barrier, no atomics. 12565 blocks x 4 waves.
__global__ __launch_bounds__(256) void k_fc2(
        const float* __restrict__ W, const float* __restrict__ v,
        const float* __restrict__ b, float* __restrict__ out) {
    int wave = threadIdx.x >> 6, lane = threadIdx.x & 63;
    int row = blockIdx.x * 4 + wave;
    if (row >= VOCAB) return;
    const float4* wr = (const float4*)(W + (size_t)row * HID);
    const float4* vv = (const float4*)v;
    float s = 0.f;
    #pragma unroll
    for (int i = 0; i < 4; ++i) {
        int idx = lane + 64 * i;
        float4 p = wr[idx], q = vv[idx];
        s += p.x * q.x + p.y * q.y + p.z * q.z + p.w * q.w;
    }
    s = wave_sum(s);
    if (lane == 0) out[row] = s + b[row];
}

// LSE stage 1: block j covers 4096 logits: local max m_j and sum_j e^(x-m_j).
// 13 blocks x 1024 threads, 1 float4/thread, ragged tail handled per-scalar.
__global__ __launch_bounds__(1024) void k_lse1(
        const float* __restrict__ logits,
        float* __restrict__ pm, float* __restrict__ ps) {
    __shared__ float red[17];
    int tid = threadIdx.x, wave = tid >> 6, lane = tid & 63;
    int i4 = blockIdx.x * 1024 + tid;
    int i0 = i4 * 4;
    float x0 = -INFINITY, x1 = -INFINITY, x2 = -INFINITY, x3 = -INFINITY;
    if (i0 + 3 < VOCAB) {
        float4 v = ((const float4*)logits)[i4];
        x0 = v.x; x1 = v.y; x2 = v.z; x3 = v.w;
    } else {
        if (i0     < VOCAB) x0 = logits[i0];
        if (i0 + 1 < VOCAB) x1 = logits[i0 + 1];
        if (i0 + 2 < VOCAB) x2 = logits[i0 + 2];
        if (i0 + 3 < VOCAB) x3 = logits[i0 + 3];
    }
    float m = fmaxf(fmaxf(x0, x1), fmaxf(x2, x3));
    m = wave_max(m);
    if (lane == 0) red[wave] = m;
    __syncthreads();
    if (tid < 64) {
        float mm = (tid < 16) ? red[tid] : -INFINITY;
        mm = wave_max(mm);
        if (tid == 0) red[16] = mm;
    }
    __syncthreads();
    m = red[16];
    // exp(-inf - m) = 0, so OOB lanes contribute nothing.
    float s = expf(x0 - m) + expf(x1 - m) + expf(x2 - m) + expf(x3 - m);
    s = wave_sum(s);
    __syncthreads();
    if (lane == 0) red[wave] = s;
    __syncthreads();
    if (tid < 64) {
        float ss = (tid < 16) ? red[tid] : 0.f;
        ss = wave_sum(ss);
        if (tid == 0) { pm[blockIdx.x] = m; ps[blockIdx.x] = ss; }
    }
}

// LSE stage 2: combine 13 partials with rescaling. One wave.
__global__ __launch_bounds__(64) void k_lse2(
        const float* __restrict__ pm, const float* __restrict__ ps,
        float* __restrict__ red_out) {
    int lane = threadIdx.x;
    float m = (lane < NLSE) ? pm[lane] : -INFINITY;
    float M = wave_max(m);
    float s = (lane < NLSE) ? ps[lane] * expf(pm[lane] - M) : 0.f;
    float S = wave_sum(s);
    if (lane == 0) { red_out[0] = M; red_out[1] = logf(S); }
}

// logp[i] = logits[i] - max - log(sumexp); float4 bulk + scalar tail
__global__ __launch_bounds__(256) void k_final(
        const float* __restrict__ logits, const float* __restrict__ red,
        float* __restrict__ out) {
    const int N4 = VOCAB / 4;
    int i = blockIdx.x * 256 + threadIdx.x;
    float c = red[0] + red[1];
    if (i < N4) {
        float4 v = ((const float4*)logits)[i];
        v.x -= c; v.y -= c; v.z -= c; v.w -= c;
        ((float4*)out)[i] = v;
    } else if (i == N4) {
        out[VOCAB - 1] = logits[VOCAB - 1] - c;
    }
}

extern "C" void kernel_launch(void* const* d_in, const int* in_sizes, int n_in,
                              void* d_out, int out_size, void* d_ws, size_t ws_size,
                              hipStream_t stream) {
    const float* attn  = (const float*)d_in[0];   // 4096 x 1024
    const float* x     = (const float*)d_in[1];   // 1024
    const float* h     = (const float*)d_in[2];   // 1024
    const float* c     = (const float*)d_in[3];   // 1024
    const float* W_ih  = (const float*)d_in[4];   // 4096 x 1024
    const float* W_hh  = (const float*)d_in[5];   // 4096 x 1024
    const float* b_ih  = (const float*)d_in[6];   // 4096
    const float* b_hh  = (const float*)d_in[7];   // 4096
    const float* fc1_w = (const float*)d_in[8];   // 1024 x 2048
    const float* fc1_b = (const float*)d_in[9];   // 1024
    const float* fc2_w = (const float*)d_in[10];  // 50257 x 1024
    const float* fc2_b = (const float*)d_in[11];  // 50257

    float* out = (float*)d_out;  // [logp 50257][h_new 1024][c_new 1024]
    float* ws  = (float*)d_ws;
    // Layout (floats). `buf` is used FIRST as ctx partials (64x1024), THEN
    // (after k_ctx_red consumes it) re-used as the logits buffer (50257).
    float* hnew   = ws;            // 1024
    float* scores = ws + 1024;     // 4096 (becomes softmax weights in place)
    float* ctx    = ws + 5120;     // 1024
    float* fc1o   = ws + 6144;     // 1024
    float* buf    = ws + 7168;     // 65536: part[64][1024] then logits[50257]
    float* pm     = ws + 72704;    // 13
    float* ps     = ws + 72720;    // 13
    float* red    = ws + 72736;    // 2

    float* part   = buf;
    float* logits = buf;

    k_gates_lstm<<<1024, 256, 0, stream>>>(W_ih, W_hh, x, h, b_ih, b_hh, c,
                                           hnew, out + VOCAB, out + VOCAB + HID);
    k_scores    <<<1024, 256, 0, stream>>>(attn, hnew, scores);
    k_softmax   <<<1, 1024, 0, stream>>>(scores);
    k_ctx_part  <<<dim3(4, 64), 256, 0, stream>>>(attn, scores, part);
    k_ctx_red   <<<4, 256, 0, stream>>>(part, ctx);
    k_fc1       <<<256, 256, 0, stream>>>(fc1_w, ctx, hnew, fc1_b, fc1o);
    k_fc2       <<<(VOCAB + 3) / 4, 256, 0, stream>>>(fc2_w, fc1o, fc2_b, logits);
    k_lse1      <<<NLSE, 1024, 0, stream>>>(logits, pm, ps);
    k_lse2      <<<1, 64, 0, stream>>>(pm, ps, red);
    k_final     <<<(VOCAB / 4 + 256) / 256, 256, 0, stream>>>(logits, red, out);
}